// Round 9
// baseline (301.507 us; speedup 1.0000x reference)
//
#include <hip/hip_runtime.h>
#include <hip/hip_bf16.h>

#define N_NODES 131072
#define N_EDGES 524288
#define DHID    128
#define DIN     256
#define VOCAB   32000

typedef __attribute__((ext_vector_type(8))) short short8;
typedef __attribute__((ext_vector_type(4))) float floatx4;

__device__ inline short bf16_rne(float f) {
    union { float f; unsigned u; } v; v.f = f;
    unsigned r = v.u + 0x7FFF + ((v.u >> 16) & 1);
    return (short)(r >> 16);
}
__device__ inline float bf16_to_f(short s) {
    union { unsigned u; float f; } v; v.u = ((unsigned)(unsigned short)s) << 16;
    return v.f;
}
__device__ inline short8 cvt8(float4 lo, float4 hi) {
    short8 o;
    o[0] = bf16_rne(lo.x); o[1] = bf16_rne(lo.y);
    o[2] = bf16_rne(lo.z); o[3] = bf16_rne(lo.w);
    o[4] = bf16_rne(hi.x); o[5] = bf16_rne(hi.y);
    o[6] = bf16_rne(hi.z); o[7] = bf16_rne(hi.w);
    return o;
}

// ---------------- edge count: int4-vectorized ----------------

__global__ __launch_bounds__(256) void count_edges(const int* __restrict__ edst,
                                                   int* __restrict__ counts) {
    int i = blockIdx.x * 256 + threadIdx.x;          // 131072 threads x 4 edges
    int4 e = ((const int4*)edst)[i];
    atomicAdd(&counts[e.x], 1);
    atomicAdd(&counts[e.y], 1);
    atomicAdd(&counts[e.z], 1);
    atomicAdd(&counts[e.w], 1);
}

// ---------------- unordered CSR allocation + metadata + ptk pack ----------------
// Offsets need only be DISJOINT, not ordered. ptk[i]=(deg<<24)|tok[i] lets
// fill do ONE random 4B gather per edge instead of two (counts[s] + tok[s]).

__global__ __launch_bounds__(256) void alloc_csr(const int* __restrict__ counts,
                                                 int* __restrict__ offsets,
                                                 int* __restrict__ cursor,
                                                 float* __restrict__ dinv,
                                                 int* __restrict__ ptk,
                                                 int* __restrict__ total,
                                                 const int* __restrict__ tok,
                                                 float* __restrict__ meta_out) {
    __shared__ int s[256];
    __shared__ int base;
    int i = blockIdx.x * 256 + threadIdx.x;
    int v = counts[i];
    s[threadIdx.x] = v;
    __syncthreads();
    for (int d = 1; d < 256; d <<= 1) {
        int t = (threadIdx.x >= d) ? s[threadIdx.x - d] : 0;
        __syncthreads();
        s[threadIdx.x] += t;
        __syncthreads();
    }
    int incl = s[threadIdx.x];
    if (threadIdx.x == 255) base = atomicAdd(total, incl);
    __syncthreads();
    int off = base + incl - v;
    offsets[i] = off;
    cursor[i]  = off;
    dinv[i] = rsqrtf((float)(v + 1));
    int tk = tok[i];
    ptk[i] = (v << 24) | tk;

    const size_t L0 = (size_t)N_NODES * DHID;
    __builtin_nontemporal_store((float)tk,         &meta_out[L0 + i]);
    __builtin_nontemporal_store(1.0f,              &meta_out[L0 + N_NODES + i]);
    __builtin_nontemporal_store((float)(i & 2047), &meta_out[L0 + 2 * N_NODES + i]);
}

// ---------------- fill_gemm: vocab GEMM || CSR fill || weight convert ----------
// CSR entry: int2 {(deg<<24)|tok[s], (deg<<24)|s} — one 8B scatter per edge.

#define FG_GEMM  250
#define FG_WCONV 128
#define FG_FILL  (N_EDGES / 256)
#define FG_TOTAL (FG_GEMM + FG_WCONV + FG_FILL)

__global__ __launch_bounds__(256) void fill_gemm(const float* __restrict__ emb,
                                                 const float* __restrict__ Wn,
                                                 short* __restrict__ z,
                                                 const float* __restrict__ W1,
                                                 const float* __restrict__ W2,
                                                 short* __restrict__ W1b,
                                                 short* __restrict__ W2b,
                                                 const int* __restrict__ src,
                                                 const int* __restrict__ dst,
                                                 int* __restrict__ cursor,
                                                 const int* __restrict__ ptk,
                                                 int2* __restrict__ csr) {
    const int b = blockIdx.x;
    if (b < FG_GEMM) {
        const int t = threadIdx.x;
        const int wid  = t >> 6;
        const int lane = t & 63;
        const int col  = lane & 15;
        const int quad = lane >> 4;
        const int vbase = b * 128 + wid * 32;
        const size_t row0 = (size_t)(vbase + col);
        const size_t row1 = (size_t)(vbase + 16 + col);

        floatx4 acc[2][8] = {};
#pragma unroll
        for (int kc = 0; kc < DIN / 32; ++kc) {
            const int ko = kc * 32 + quad * 8;
            short8 a0 = cvt8(*(const float4*)&emb[row0 * DIN + ko],
                             *(const float4*)&emb[row0 * DIN + ko + 4]);
            short8 a1 = cvt8(*(const float4*)&emb[row1 * DIN + ko],
                             *(const float4*)&emb[row1 * DIN + ko + 4]);
#pragma unroll
            for (int ft = 0; ft < 8; ++ft) {
                const size_t wr = (size_t)(col * 8 + ft) * DIN + ko;
                short8 bb = cvt8(*(const float4*)&Wn[wr],
                                 *(const float4*)&Wn[wr + 4]);
                acc[0][ft] = __builtin_amdgcn_mfma_f32_16x16x32_bf16(a0, bb, acc[0][ft], 0, 0, 0);
                acc[1][ft] = __builtin_amdgcn_mfma_f32_16x16x32_bf16(a1, bb, acc[1][ft], 0, 0, 0);
            }
        }
        // NO bias: bn folds into conv1 via sw.
#pragma unroll
        for (int mt = 0; mt < 2; ++mt) {
#pragma unroll
            for (int r = 0; r < 4; ++r) {
                const int row = vbase + mt * 16 + quad * 4 + r;
                short8 o;
#pragma unroll
                for (int ft = 0; ft < 8; ++ft)
                    o[ft] = bf16_rne(acc[mt][ft][r]);
                *(short8*)&z[(size_t)row * DHID + col * 8] = o;
            }
        }
    } else if (b < FG_GEMM + FG_WCONV) {
        int i = (b - FG_GEMM) * 256 + threadIdx.x;   // 32768 total
        if (i < 16384) W1b[i] = bf16_rne(W1[i]);
        else           W2b[i - 16384] = bf16_rne(W2[i - 16384]);
    } else {
        int e = (b - FG_GEMM - FG_WCONV) * 256 + threadIdx.x;
        int d = dst[e];
        int s = src[e];
        int p = atomicAdd(&cursor[d], 1);
        int pt = ptk[s];                              // ONE random 4B gather
        csr[p] = make_int2(pt, (pt & 0xFF000000) | s);
    }
}

// ---------------- fused GCN conv ----------------
// ZG (conv1): TOKEN-RANGE BLOCKED 3-pass gather. z (7.8MB) doesn't fit a
//   4MB per-XCD L2 -> conv1's FETCH was 51MB of L2 refill (the ~2.1TB/s
//   fill-path wall). Each pass gathers only tokens in a 2.7MB z-slice that
//   IS L2-resident; extra cost = 3x CSR walk (streamed) + loop VALU (16%
//   busy, headroom). x2b stores nontemporal so they don't evict the slice.
//   Discriminator: FETCH->12MB & dur->~35us = fill wall; dur flat = request
//   wall (convs structurally done).
// !ZG (conv2): original loop (33.5MB working set can't be sliced cheaply).

template <bool RELU, bool OUT_BF16, bool ZG>
__global__ __launch_bounds__(256, 8) void fused_conv(const short* __restrict__ x,
                                                     const int2* __restrict__ csr,
                                                     const int* __restrict__ offsets,
                                                     const int* __restrict__ counts,
                                                     const float* __restrict__ dinv,
                                                     const int* __restrict__ tok,
                                                     const float* __restrict__ bn,
                                                     const short* __restrict__ Wb,
                                                     const float* __restrict__ bias,
                                                     void* __restrict__ outp) {
    const int t = threadIdx.x;
    const int wid  = t >> 6;
    const int lane = t & 63;
    const int col  = lane & 15;
    const int quad = lane >> 4;
    const int base = (blockIdx.x * 4 + wid) * 16;
    const int node = base + col;

    const float di = dinv[node];
    const int beg = offsets[node];
    const int cnt = counts[node];
    const int2* pcsr = csr + beg;

    float af[4][8] = {};
    float sw = di;   // ZG only: running norm sum for exact bn fold

    if constexpr (ZG) {
        const int selftok = tok[node];
        const int PR = (VOCAB + 2) / 3;              // 10667-token slices
#pragma unroll 1
        for (int p = 0; p < 3; ++p) {
            const int lo = p * PR;
            const int hi = lo + PR;
            if (selftok >= lo && selftok < hi) {     // self row in this slice?
                const size_t xrow = (size_t)selftok * DHID + quad * 8;
#pragma unroll
                for (int c = 0; c < 4; ++c) {
                    short8 v = *(const short8*)&x[xrow + c * 32];
#pragma unroll
                    for (int j = 0; j < 8; ++j)
                        af[c][j] = fmaf(di, bf16_to_f(v[j]), af[c][j]);
                }
            }
            for (int e = 0; e < cnt; ++e) {
                const int ce = ((const int*)pcsr)[2 * e];      // .x = tok-packed
                const int s  = ce & 0xFFFFFF;
                if (s >= lo && s < hi) {
                    const float w = rsqrtf((float)(((unsigned)ce >> 24) + 1));
                    sw += w;
                    const size_t r0 = (size_t)s * DHID + quad * 8;
                    short8 u0 = *(const short8*)&x[r0];
                    short8 u1 = *(const short8*)&x[r0 + 32];
                    short8 u2 = *(const short8*)&x[r0 + 64];
                    short8 u3 = *(const short8*)&x[r0 + 96];
#pragma unroll
                    for (int j = 0; j < 8; ++j) {
                        af[0][j] = fmaf(w, bf16_to_f(u0[j]), af[0][j]);
                        af[1][j] = fmaf(w, bf16_to_f(u1[j]), af[1][j]);
                        af[2][j] = fmaf(w, bf16_to_f(u2[j]), af[2][j]);
                        af[3][j] = fmaf(w, bf16_to_f(u3[j]), af[3][j]);
                    }
                }
            }
        }
    } else {
        // self-loop init
        {
            const size_t xrow = (size_t)node * DHID + quad * 8;
#pragma unroll
            for (int c = 0; c < 4; ++c) {
                short8 v = *(const short8*)&x[xrow + c * 32];
#pragma unroll
                for (int j = 0; j < 8; ++j) af[c][j] = di * bf16_to_f(v[j]);
            }
        }
        // edge loop: 1-ahead prefetch on the .y (node-packed) halves
        int cn = (cnt > 0) ? ((const int*)pcsr)[1] : 0;
        for (int e = 0; e < cnt; ++e) {
            const int   s = cn & 0xFFFFFF;
            const float w = rsqrtf((float)(((unsigned)cn >> 24) + 1));
            if (e + 1 < cnt) cn = ((const int*)pcsr)[2 * e + 3];
            const size_t r0 = (size_t)s * DHID + quad * 8;
            short8 u0 = *(const short8*)&x[r0];
            short8 u1 = *(const short8*)&x[r0 + 32];
            short8 u2 = *(const short8*)&x[r0 + 64];
            short8 u3 = *(const short8*)&x[r0 + 96];
#pragma unroll
            for (int j = 0; j < 8; ++j) {
                af[0][j] = fmaf(w, bf16_to_f(u0[j]), af[0][j]);
                af[1][j] = fmaf(w, bf16_to_f(u1[j]), af[1][j]);
                af[2][j] = fmaf(w, bf16_to_f(u2[j]), af[2][j]);
                af[3][j] = fmaf(w, bf16_to_f(u3[j]), af[3][j]);
            }
        }
    }

    // fold outer di (+ sw*bn for ZG) and round A-fragments to bf16
    short8 a[4];
#pragma unroll
    for (int c = 0; c < 4; ++c) {
        if (ZG) {
            const float4 b0 = *(const float4*)&bn[c * 32 + quad * 8];
            const float4 b1 = *(const float4*)&bn[c * 32 + quad * 8 + 4];
            const float bv[8] = {b0.x, b0.y, b0.z, b0.w, b1.x, b1.y, b1.z, b1.w};
#pragma unroll
            for (int j = 0; j < 8; ++j)
                a[c][j] = bf16_rne(di * (af[c][j] + sw * bv[j]));
        } else {
#pragma unroll
            for (int j = 0; j < 8; ++j) a[c][j] = bf16_rne(di * af[c][j]);
        }
    }

    // MFMA with weights (L1-hot). B-row remap (row = col*8+ft).
    floatx4 acc[8] = {};
#pragma unroll
    for (int c = 0; c < 4; ++c) {
        const int ko = c * 32 + quad * 8;
#pragma unroll
        for (int ft = 0; ft < 8; ++ft) {
            short8 b = *(const short8*)&Wb[(size_t)(col * 8 + ft) * DHID + ko];
            acc[ft] = __builtin_amdgcn_mfma_f32_16x16x32_bf16(a[c], b, acc[ft], 0, 0, 0);
        }
    }

    // epilogue
    const float4 bv0 = *(const float4*)&bias[col * 8];
    const float4 bv1 = *(const float4*)&bias[col * 8 + 4];
    const float bb[8] = {bv0.x, bv0.y, bv0.z, bv0.w, bv1.x, bv1.y, bv1.z, bv1.w};
    short* outb = (short*)outp;
    float* outf = (float*)outp;
#pragma unroll
    for (int r = 0; r < 4; ++r) {
        const size_t row = (size_t)(base + quad * 4 + r) * DHID + col * 8;
        if (OUT_BF16) {
            // conv1 out (x2b): nontemporal — don't evict the L2 z-slice;
            // conv2's x2b reads were L3-served anyway.
            short8 o;
#pragma unroll
            for (int ft = 0; ft < 8; ++ft) {
                float v = acc[ft][r] + bb[ft];
                if (RELU) v = fmaxf(v, 0.f);
                o[ft] = bf16_rne(v);
            }
            __builtin_nontemporal_store(o, (short8*)&outb[row]);
        } else {
            floatx4 o0, o1;
            o0[0] = acc[0][r] + bb[0]; o0[1] = acc[1][r] + bb[1];
            o0[2] = acc[2][r] + bb[2]; o0[3] = acc[3][r] + bb[3];
            o1[0] = acc[4][r] + bb[4]; o1[1] = acc[5][r] + bb[5];
            o1[2] = acc[6][r] + bb[6]; o1[3] = acc[7][r] + bb[7];
            if (RELU) {
#pragma unroll
                for (int k = 0; k < 4; ++k) {
                    o0[k] = fmaxf(o0[k], 0.f);
                    o1[k] = fmaxf(o1[k], 0.f);
                }
            }
            __builtin_nontemporal_store(o0, (floatx4*)&outf[row]);
            __builtin_nontemporal_store(o1, (floatx4*)&outf[row + 4]);
        }
    }
}

// ---------------- launch ----------------

extern "C" void kernel_launch(void* const* d_in, const int* in_sizes, int n_in,
                              void* d_out, int out_size, void* d_ws, size_t ws_size,
                              hipStream_t stream) {
    const int*   tok  = (const int*)d_in[0];
    const int*   esrc = (const int*)d_in[1];
    const int*   edst = esrc + N_EDGES;
    const float* emb  = (const float*)d_in[2];
    const float* Wn   = (const float*)d_in[3];
    const float* bn   = (const float*)d_in[4];
    const float* W1   = (const float*)d_in[5];
    const float* b1   = (const float*)d_in[6];
    const float* W2   = (const float*)d_in[7];
    const float* b2   = (const float*)d_in[8];
    float* out = (float*)d_out;

    char* ws = (char*)d_ws;
    int*   counts  = (int*)(ws);                              // 512 KB @0
    int*   total   = (int*)(ws + (1u << 19));                 // 256 B  @0.5MB (zeroed w/ counts)
    int*   offsets = (int*)(ws + (1u << 19) + 256);           // 512 KB
    int*   cursor  = (int*)(ws + (2u << 19) + 256);           // 512 KB
    float* dinv    = (float*)(ws + (3u << 19) + 256);         // 512 KB
    int*   ptk     = (int*)(ws + (4u << 19) + 256);           // 512 KB
    int2*  csr     = (int2*)(ws + 3 * (1u << 20));            // 4 MB @3MB
    short* W1b     = (short*)(ws + 7 * (1u << 20));           // 32 KB @7MB
    short* W2b     = (short*)(ws + 7 * (1u << 20) + (1u << 15)); // 32 KB
    short* z       = (short*)(ws + 8 * (1u << 20));           // 7.8 MB @8MB
    short* x2b     = (short*)(ws + 16 * (1u << 20));          // 33.5 MB @16MB

    hipMemsetAsync(counts, 0, (1u << 19) + 256, stream);
    count_edges<<<N_EDGES / 1024, 256, 0, stream>>>(edst, counts);
    alloc_csr<<<N_NODES / 256, 256, 0, stream>>>(counts, offsets, cursor, dinv,
                                                 ptk, total, tok, out);
    fill_gemm<<<FG_TOTAL, 256, 0, stream>>>(emb, Wn, z, W1, W2, W1b, W2b,
                                            esrc, edst, cursor, ptk, csr);

    // conv1: token-range-blocked z-gather + bn fold, relu -> x2b (nt)
    fused_conv<true, true, true><<<N_NODES / 64, 256, 0, stream>>>(
        z, csr, offsets, counts, dinv, tok, bn, W1b, b1, x2b);
    // conv2: x2b-gather, fp32 nontemporal out -> d_out
    fused_conv<false, false, false><<<N_NODES / 64, 256, 0, stream>>>(
        x2b, csr, offsets, counts, dinv, tok, bn, W2b, b2, out);
}

// Round 10
// 286.173 us; speedup vs baseline: 1.0536x; 1.0536x over previous
//
#include <hip/hip_runtime.h>
#include <hip/hip_bf16.h>

#define N_NODES 131072
#define N_EDGES 524288
#define DHID    128
#define DIN     256
#define VOCAB   32000

typedef __attribute__((ext_vector_type(8))) short short8;
typedef __attribute__((ext_vector_type(4))) float floatx4;

__device__ inline short bf16_rne(float f) {
    union { float f; unsigned u; } v; v.f = f;
    unsigned r = v.u + 0x7FFF + ((v.u >> 16) & 1);
    return (short)(r >> 16);
}
__device__ inline float bf16_to_f(short s) {
    union { unsigned u; float f; } v; v.u = ((unsigned)(unsigned short)s) << 16;
    return v.f;
}
__device__ inline short8 cvt8(float4 lo, float4 hi) {
    short8 o;
    o[0] = bf16_rne(lo.x); o[1] = bf16_rne(lo.y);
    o[2] = bf16_rne(lo.z); o[3] = bf16_rne(lo.w);
    o[4] = bf16_rne(hi.x); o[5] = bf16_rne(hi.y);
    o[6] = bf16_rne(hi.z); o[7] = bf16_rne(hi.w);
    return o;
}

// ---------------- mega: vocab GEMM || weight convert || edge count ----------
// Round-5-proven structure (best total, 286.8us): scalar count (2048 blocks,
// 1 atomic/thread — max parallelism for the latency-bound atomic path)
// overlapped with the dense vocab GEMM. Round-8's int4 count on 512 blocks
// was latency-starved — reverted.

#define MG_GEMM  250
#define MG_WCONV 128
#define MG_COUNT (N_EDGES / 256)
#define MG_TOTAL (MG_GEMM + MG_WCONV + MG_COUNT)

__global__ __launch_bounds__(256) void mega(const float* __restrict__ emb,
                                            const float* __restrict__ Wn,
                                            short* __restrict__ z,
                                            const float* __restrict__ W1,
                                            const float* __restrict__ W2,
                                            short* __restrict__ W1b,
                                            short* __restrict__ W2b,
                                            const int* __restrict__ edst,
                                            int* __restrict__ counts) {
    const int b = blockIdx.x;
    if (b < MG_GEMM) {
        // z[v] = bf16(emb[v] @ Wn^T), 128 rows/block, fp32 converted in-reg.
        const int t = threadIdx.x;
        const int wid  = t >> 6;
        const int lane = t & 63;
        const int col  = lane & 15;
        const int quad = lane >> 4;
        const int vbase = b * 128 + wid * 32;
        const size_t row0 = (size_t)(vbase + col);
        const size_t row1 = (size_t)(vbase + 16 + col);

        floatx4 acc[2][8] = {};
#pragma unroll
        for (int kc = 0; kc < DIN / 32; ++kc) {
            const int ko = kc * 32 + quad * 8;
            short8 a0 = cvt8(*(const float4*)&emb[row0 * DIN + ko],
                             *(const float4*)&emb[row0 * DIN + ko + 4]);
            short8 a1 = cvt8(*(const float4*)&emb[row1 * DIN + ko],
                             *(const float4*)&emb[row1 * DIN + ko + 4]);
#pragma unroll
            for (int ft = 0; ft < 8; ++ft) {
                const size_t wr = (size_t)(col * 8 + ft) * DIN + ko;
                short8 bb = cvt8(*(const float4*)&Wn[wr],
                                 *(const float4*)&Wn[wr + 4]);
                acc[0][ft] = __builtin_amdgcn_mfma_f32_16x16x32_bf16(a0, bb, acc[0][ft], 0, 0, 0);
                acc[1][ft] = __builtin_amdgcn_mfma_f32_16x16x32_bf16(a1, bb, acc[1][ft], 0, 0, 0);
            }
        }
        // NO bias: bn folds into conv1 via sw.
#pragma unroll
        for (int mt = 0; mt < 2; ++mt) {
#pragma unroll
            for (int r = 0; r < 4; ++r) {
                const int row = vbase + mt * 16 + quad * 4 + r;
                short8 o;
#pragma unroll
                for (int ft = 0; ft < 8; ++ft)
                    o[ft] = bf16_rne(acc[mt][ft][r]);
                *(short8*)&z[(size_t)row * DHID + col * 8] = o;
            }
        }
    } else if (b < MG_GEMM + MG_WCONV) {
        int i = (b - MG_GEMM) * 256 + threadIdx.x;   // 32768 total
        if (i < 16384) W1b[i] = bf16_rne(W1[i]);
        else           W2b[i - 16384] = bf16_rne(W2[i - 16384]);
    } else {
        int e = (b - MG_GEMM - MG_WCONV) * 256 + threadIdx.x;
        atomicAdd(&counts[edst[e]], 1);
    }
}

// ---------------- unordered CSR allocation + metadata + ptk pack ----------------
// Offsets need only be DISJOINT, not ordered: block LDS scan + one global
// atomicAdd per block. ptk[i]=(deg<<24)|tok[i] gives fill ONE random 4B
// gather per edge. Metadata folded in (final output -> nontemporal).

__global__ __launch_bounds__(256) void alloc_csr(const int* __restrict__ counts,
                                                 int* __restrict__ offsets,
                                                 int* __restrict__ cursor,
                                                 float* __restrict__ dinv,
                                                 int* __restrict__ ptk,
                                                 int* __restrict__ total,
                                                 const int* __restrict__ tok,
                                                 float* __restrict__ meta_out) {
    __shared__ int s[256];
    __shared__ int base;
    int i = blockIdx.x * 256 + threadIdx.x;
    int v = counts[i];
    s[threadIdx.x] = v;
    __syncthreads();
    for (int d = 1; d < 256; d <<= 1) {
        int t = (threadIdx.x >= d) ? s[threadIdx.x - d] : 0;
        __syncthreads();
        s[threadIdx.x] += t;
        __syncthreads();
    }
    int incl = s[threadIdx.x];
    if (threadIdx.x == 255) base = atomicAdd(total, incl);
    __syncthreads();
    int off = base + incl - v;
    offsets[i] = off;
    cursor[i]  = off;
    dinv[i] = rsqrtf((float)(v + 1));
    int tk = tok[i];
    ptk[i] = (v << 24) | tk;

    const size_t L0 = (size_t)N_NODES * DHID;
    __builtin_nontemporal_store((float)tk,         &meta_out[L0 + i]);
    __builtin_nontemporal_store(1.0f,              &meta_out[L0 + N_NODES + i]);
    __builtin_nontemporal_store((float)(i & 2047), &meta_out[L0 + 2 * N_NODES + i]);
}

// ---------------- CSR fill ----------------
// int2 entry {(deg<<24)|tok[s], (deg<<24)|s}: one 4B gather (ptk) + one 8B
// scatter per edge; w = rsqrt(deg+1) recomputed in-conv (VALU has headroom).

__global__ __launch_bounds__(256) void fill_csr(const int* __restrict__ src,
                                                const int* __restrict__ dst,
                                                int* __restrict__ cursor,
                                                const int* __restrict__ ptk,
                                                int2* __restrict__ csr) {
    int e = blockIdx.x * 256 + threadIdx.x;
    int d = dst[e];
    int s = src[e];
    int p = atomicAdd(&cursor[d], 1);
    int pt = ptk[s];
    csr[p] = make_int2(pt, (pt & 0xFF000000) | s);
}

// ---------------- fused GCN conv ----------------
// STRUCTURAL WALL (rounds 0-9, measured): the gather loop is pinned at
// ~2.2 TB/s of 64B-line request demand per conv, INDEPENDENT of cache tier
// (r7: conv1 @1.45 TB/s HBM = conv2 @2.7 TB/s = 64us), occupancy (25-76%),
// node ordering (r3), unroll depth (r1), and L2-blocking (r9: FETCH -25%,
// time +16% from 3x loop overhead). Requests are already maximally efficient
// (4 lanes x 16B per 64B line; 4 lines per 256B row irreducible). Single-pass
// loop + 8 waves/SIMD is the optimum found. Leave alone.
// ZG (conv1): z-gather via tok idx (.x); bn folded via sw = di + sum(w).
// !ZG (conv2): x-gather via node idx (.y); fp32 nontemporal out.

template <bool RELU, bool OUT_BF16, bool ZG>
__global__ __launch_bounds__(256, 8) void fused_conv(const short* __restrict__ x,
                                                     const int2* __restrict__ csr,
                                                     const int* __restrict__ offsets,
                                                     const int* __restrict__ counts,
                                                     const float* __restrict__ dinv,
                                                     const int* __restrict__ tok,
                                                     const float* __restrict__ bn,
                                                     const short* __restrict__ Wb,
                                                     const float* __restrict__ bias,
                                                     void* __restrict__ outp) {
    const int t = threadIdx.x;
    const int wid  = t >> 6;
    const int lane = t & 63;
    const int col  = lane & 15;
    const int quad = lane >> 4;
    const int base = (blockIdx.x * 4 + wid) * 16;
    const int node = base + col;

    const float di = dinv[node];
    const int beg = offsets[node];
    const int cnt = counts[node];
    const int2* pcsr = csr + beg;

    // self-loop init: af = di * row_self
    float af[4][8];
    {
        const int self = ZG ? tok[node] : node;
        const size_t xrow = (size_t)self * DHID + quad * 8;
#pragma unroll
        for (int c = 0; c < 4; ++c) {
            short8 v = *(const short8*)&x[xrow + c * 32];
#pragma unroll
            for (int j = 0; j < 8; ++j) af[c][j] = di * bf16_to_f(v[j]);
        }
    }
    float sw = di;   // ZG only: running norm sum for exact bn fold

    // edge loop: packed int2 entry, 1-ahead prefetch, w via v_rsq
    int2 cn = (cnt > 0) ? pcsr[0] : make_int2(0, 0);
    for (int e = 0; e < cnt; ++e) {
        const int   ce = ZG ? cn.x : cn.y;
        const int   s  = ce & 0xFFFFFF;
        const float w  = rsqrtf((float)(((unsigned)ce >> 24) + 1));
        if (e + 1 < cnt) cn = pcsr[e + 1];
        if (ZG) sw += w;
        const size_t r0 = (size_t)s * DHID + quad * 8;
        short8 u0 = *(const short8*)&x[r0];
        short8 u1 = *(const short8*)&x[r0 + 32];
        short8 u2 = *(const short8*)&x[r0 + 64];
        short8 u3 = *(const short8*)&x[r0 + 96];
#pragma unroll
        for (int j = 0; j < 8; ++j) {
            af[0][j] = fmaf(w, bf16_to_f(u0[j]), af[0][j]);
            af[1][j] = fmaf(w, bf16_to_f(u1[j]), af[1][j]);
            af[2][j] = fmaf(w, bf16_to_f(u2[j]), af[2][j]);
            af[3][j] = fmaf(w, bf16_to_f(u3[j]), af[3][j]);
        }
    }

    // fold outer di (+ sw*bn for ZG) and round A-fragments to bf16
    short8 a[4];
#pragma unroll
    for (int c = 0; c < 4; ++c) {
        if (ZG) {
            const float4 b0 = *(const float4*)&bn[c * 32 + quad * 8];
            const float4 b1 = *(const float4*)&bn[c * 32 + quad * 8 + 4];
            const float bv[8] = {b0.x, b0.y, b0.z, b0.w, b1.x, b1.y, b1.z, b1.w};
#pragma unroll
            for (int j = 0; j < 8; ++j)
                a[c][j] = bf16_rne(di * (af[c][j] + sw * bv[j]));
        } else {
#pragma unroll
            for (int j = 0; j < 8; ++j) a[c][j] = bf16_rne(di * af[c][j]);
        }
    }

    // MFMA with weights (L1-hot). B-row remap (row = col*8+ft): lane's outputs
    // across ft are consecutive features -> 16B/32B contiguous stores.
    floatx4 acc[8] = {};
#pragma unroll
    for (int c = 0; c < 4; ++c) {
        const int ko = c * 32 + quad * 8;
#pragma unroll
        for (int ft = 0; ft < 8; ++ft) {
            short8 b = *(const short8*)&Wb[(size_t)(col * 8 + ft) * DHID + ko];
            acc[ft] = __builtin_amdgcn_mfma_f32_16x16x32_bf16(a[c], b, acc[ft], 0, 0, 0);
        }
    }

    // epilogue: D rows m=quad*4+r are nodes base+quad*4+r; features col*8..+7
    const float4 bv0 = *(const float4*)&bias[col * 8];
    const float4 bv1 = *(const float4*)&bias[col * 8 + 4];
    const float bb[8] = {bv0.x, bv0.y, bv0.z, bv0.w, bv1.x, bv1.y, bv1.z, bv1.w};
    short* outb = (short*)outp;
    float* outf = (float*)outp;
#pragma unroll
    for (int r = 0; r < 4; ++r) {
        const size_t row = (size_t)(base + quad * 4 + r) * DHID + col * 8;
        if (OUT_BF16) {
            // conv1 out (x2b): re-read by conv2 -> keep cached (normal store)
            short8 o;
#pragma unroll
            for (int ft = 0; ft < 8; ++ft) {
                float v = acc[ft][r] + bb[ft];
                if (RELU) v = fmaxf(v, 0.f);
                o[ft] = bf16_rne(v);
            }
            *(short8*)&outb[row] = o;
        } else {
            // conv2 out: final output, never re-read -> nontemporal
            floatx4 o0, o1;
            o0[0] = acc[0][r] + bb[0]; o0[1] = acc[1][r] + bb[1];
            o0[2] = acc[2][r] + bb[2]; o0[3] = acc[3][r] + bb[3];
            o1[0] = acc[4][r] + bb[4]; o1[1] = acc[5][r] + bb[5];
            o1[2] = acc[6][r] + bb[6]; o1[3] = acc[7][r] + bb[7];
            if (RELU) {
#pragma unroll
                for (int k = 0; k < 4; ++k) {
                    o0[k] = fmaxf(o0[k], 0.f);
                    o1[k] = fmaxf(o1[k], 0.f);
                }
            }
            __builtin_nontemporal_store(o0, (floatx4*)&outf[row]);
            __builtin_nontemporal_store(o1, (floatx4*)&outf[row + 4]);
        }
    }
}

// ---------------- launch ----------------

extern "C" void kernel_launch(void* const* d_in, const int* in_sizes, int n_in,
                              void* d_out, int out_size, void* d_ws, size_t ws_size,
                              hipStream_t stream) {
    const int*   tok  = (const int*)d_in[0];
    const int*   esrc = (const int*)d_in[1];
    const int*   edst = esrc + N_EDGES;
    const float* emb  = (const float*)d_in[2];
    const float* Wn   = (const float*)d_in[3];
    const float* bn   = (const float*)d_in[4];
    const float* W1   = (const float*)d_in[5];
    const float* b1   = (const float*)d_in[6];
    const float* W2   = (const float*)d_in[7];
    const float* b2   = (const float*)d_in[8];
    float* out = (float*)d_out;

    char* ws = (char*)d_ws;
    int*   counts  = (int*)(ws);                              // 512 KB @0
    int*   total   = (int*)(ws + (1u << 19));                 // 256 B  @0.5MB (zeroed w/ counts)
    int*   offsets = (int*)(ws + (1u << 19) + 256);           // 512 KB
    int*   cursor  = (int*)(ws + (2u << 19) + 256);           // 512 KB
    float* dinv    = (float*)(ws + (3u << 19) + 256);         // 512 KB
    int*   ptk     = (int*)(ws + (4u << 19) + 256);           // 512 KB
    int2*  csr     = (int2*)(ws + 3 * (1u << 20));            // 4 MB @3MB
    short* W1b     = (short*)(ws + 7 * (1u << 20));           // 32 KB @7MB
    short* W2b     = (short*)(ws + 7 * (1u << 20) + (1u << 15)); // 32 KB
    short* z       = (short*)(ws + 8 * (1u << 20));           // 7.8 MB @8MB
    short* x2b     = (short*)(ws + 16 * (1u << 20));          // 33.5 MB @16MB

    hipMemsetAsync(counts, 0, (1u << 19) + 256, stream);
    // vocab GEMM || weight convert || scalar edge count (round-5 structure)
    mega<<<MG_TOTAL, 256, 0, stream>>>(emb, Wn, z, W1, W2, W1b, W2b, edst, counts);
    alloc_csr<<<N_NODES / 256, 256, 0, stream>>>(counts, offsets, cursor, dinv,
                                                 ptk, total, tok, out);
    fill_csr<<<N_EDGES / 256, 256, 0, stream>>>(esrc, edst, cursor, ptk, csr);

    // conv1: z-gather (tok idx) + bn fold, relu -> x2b (cached)
    fused_conv<true, true, true><<<N_NODES / 64, 256, 0, stream>>>(
        z, csr, offsets, counts, dinv, tok, bn, W1b, b1, x2b);
    // conv2: x2b-gather (node idx), fp32 nontemporal out -> d_out
    fused_conv<false, false, false><<<N_NODES / 64, 256, 0, stream>>>(
        x2b, csr, offsets, counts, dinv, tok, bn, W2b, b2, out);
}